// Round 6
// baseline (11385.213 us; speedup 1.0000x reference)
//
#include <hip/hip_runtime.h>
#include <math.h>

// Persistent greedy transformer decoder, MI355X (gfx950).
// B=8, D=512, NH=8 (hd=64), H=2048, NL=2, V=32000, L=48.
// Round-7: 64-block single domain (round-3 base, best=5541us), restructured
// to 5 barriers/step (was 9) via batch-local + XCD-aligned column-slicing:
//   block (ab,ah) = (widx>>3, widx&7); XCD = widx%8 == ah.
//   - QKV+attn: local (unchanged). Attn out -> LDS o_s, NOT workspace.
//   - out-proj: column-slice partial p1[ab][ah][512] from local o_s
//     (weights cols ah*64..+64 shared by the 8 same-ah blocks = same XCD L2).
//     Barrier A deleted; partials summed at LN1 read.
//   - FF1: rows [ah*256,+256) of OWN batch -> hff slice stays in LDS.
//   - FF2: column-slice partial p2[ab][ah][512]. Barriers B/C deleted.
//   - next-layer input / final x3 rebuilt from p2 partials (+x2 publish by
//     ah==0 blocks for the all-batch x3 the logits GEMV needs).
//   - logits: round-3's 500-row contiguous slab + LDS tile + coalesced NT
//     stores + 64x8 candidate reduce. Unchanged.
// Barriers/step: X1,X2 (layer0), X1,X2 (layer1), E = 5.

#define NBK 64
#define NTH 512
#define NGRP 32

namespace cfg {
constexpr int D  = 512;
constexpr int HF = 2048;
constexpr int V  = 32000;
constexpr int TMAX = 64;        // LDS KV slots (>= L)
constexpr int VPB  = V / NBK;   // 500 logits rows per block
constexpr float EPS = 1e-5f;
constexpr float PE_NEG = -0.017988946039015984f;  // -ln(10000)/512

// workspace float offsets; u32 [0..2047] = barrier flags (64 x 128B)
constexpr size_t O_CAV  = 2048;
constexpr size_t O_CAC  = O_CAV + 2 * 8 * 512;
constexpr size_t O_P1   = O_CAC + 2 * 8 * 512;   // [8][8][512] out-proj partials
constexpr size_t O_P2   = O_P1  + 64 * 512;      // [8][8][512] FF2 partials
constexpr size_t O_X2P  = O_P2  + 64 * 512;      // [8][512] published x2 (layer1)
constexpr size_t O_CAND = O_X2P + 8 * 512;
}

typedef float f4v __attribute__((ext_vector_type(4)));

// device-coherent (cross-XCD) accesses for inter-block communication
__device__ __forceinline__ float ld_dev(const float* p) {
  return __hip_atomic_load(p, __ATOMIC_RELAXED, __HIP_MEMORY_SCOPE_AGENT);
}
__device__ __forceinline__ void st_dev(float* p, float v) {
  __hip_atomic_store(p, v, __ATOMIC_RELAXED, __HIP_MEMORY_SCOPE_AGENT);
}
union F2U { float2 f; unsigned long long u; };
__device__ __forceinline__ float2 ld_dev2(const float2* p) {
  F2U x; x.u = __hip_atomic_load((const unsigned long long*)p, __ATOMIC_RELAXED, __HIP_MEMORY_SCOPE_AGENT);
  return x.f;
}
__device__ __forceinline__ void st_dev2(float2* p, float2 v) {
  F2U x; x.f = v;
  __hip_atomic_store((unsigned long long*)p, x.u, __ATOMIC_RELAXED, __HIP_MEMORY_SCOPE_AGENT);
}
__device__ __forceinline__ unsigned ld_devu(const unsigned* p) {
  return __hip_atomic_load(p, __ATOMIC_RELAXED, __HIP_MEMORY_SCOPE_AGENT);
}
__device__ __forceinline__ void st_devu(unsigned* p, unsigned v) {
  __hip_atomic_store(p, v, __ATOMIC_RELAXED, __HIP_MEMORY_SCOPE_AGENT);
}

__launch_bounds__(NTH)
__global__ void decoder_persistent(
    const float* __restrict__ memory, const float* __restrict__ embedding,
    const float* __restrict__ sa_in_w, const float* __restrict__ sa_in_b,
    const float* __restrict__ sa_out_w, const float* __restrict__ sa_out_b,
    const float* __restrict__ ca_in_w, const float* __restrict__ ca_in_b,
    const float* __restrict__ ca_out_w, const float* __restrict__ ca_out_b,
    const float* __restrict__ ff1_w, const float* __restrict__ ff1_b,
    const float* __restrict__ ff2_w, const float* __restrict__ ff2_b,
    const float* __restrict__ ln1_g, const float* __restrict__ ln1_b,
    const float* __restrict__ ln2_g, const float* __restrict__ ln2_b,
    const float* __restrict__ ln3_g, const float* __restrict__ ln3_b,
    const float* __restrict__ out_w, const float* __restrict__ out_b,
    const int* __restrict__ max_len_p,
    float* __restrict__ dout, float* __restrict__ wsf) {
  using namespace cfg;
  __shared__ __align__(16) float xs[8192];            // 32 KB activations
  __shared__ float kch[2][TMAX][64];                  // 16 KB LDS K cache
  __shared__ float vch[2][TMAX][64];                  // 16 KB LDS V cache
  __shared__ float ltile[8][VPB + 16];                // 16.5 KB logits tile
  __shared__ __align__(16) float hffs[256];           // own-batch FF1 slice
  __shared__ __align__(16) float o_s[64];             // attn output slice
  __shared__ float q_s[64];
  __shared__ float p_l[64];
  __shared__ float div_ls[256];                       // PE frequency table
  __shared__ float2 redc[64];
  __shared__ float2 gcand[NGRP * 8];
  __shared__ int tok_ls[8];

  const int tid  = threadIdx.x;
  const int w    = tid >> 6;    // wave id
  const int lane = tid & 63;
  const int col0 = lane * 8;
  const int gl   = tid & 15;
  const int grp  = tid >> 4;
  const int L    = max_len_p[0];
  const int widx = (int)blockIdx.x;
  const int ab = widx >> 3;     // block's batch
  const int ah = widx & 7;      // block's head (== XCD: widx%8)

  unsigned* wflag = (unsigned*)wsf;   // 64 flags, stride 32 u32 (128 B)

  float*  cav  = wsf + O_CAV;
  float*  cac  = wsf + O_CAC;
  float*  p1w  = wsf + O_P1;
  float*  p2w  = wsf + O_P2;
  float*  x2pb = wsf + O_X2P;
  float2* cand = (float2*)(wsf + O_CAND);
  float*  dlog = dout + (size_t)8 * L;

  unsigned wbarn = 0;

  // RMW-free 64-block flag barrier (round-4 mechanism, proven).
  auto wsync = [&]() {
    __syncthreads();
    ++wbarn;
    if (tid == 0) st_devu(&wflag[widx * 32], wbarn);
    if (w == 0) {
      while (true) {
        const unsigned v = ld_devu(&wflag[lane * 32]);
        if (__ballot(v < wbarn) == 0ull) break;
        __builtin_amdgcn_s_sleep(1);
      }
    }
    __syncthreads();
  };

  // wave-local LayerNorm of v[8] (cols col0..col0+7 of one row)
  auto wave_ln = [&](float (&v)[8], const float* g, const float* bta) {
    float s = 0.f, s2 = 0.f;
#pragma unroll
    for (int j = 0; j < 8; ++j) { s += v[j]; s2 = fmaf(v[j], v[j], s2); }
#pragma unroll
    for (int m = 1; m < 64; m <<= 1) { s += __shfl_xor(s, m); s2 += __shfl_xor(s2, m); }
    const float mean = s * (1.f / 512.f);
    const float var  = s2 * (1.f / 512.f) - mean * mean;
    const float inv  = 1.0f / sqrtf(var + EPS);
    const float4 g0 = ((const float4*)(g + col0))[0], g1 = ((const float4*)(g + col0))[1];
    const float4 b0 = ((const float4*)(bta + col0))[0], b1 = ((const float4*)(bta + col0))[1];
    const float gg[8] = {g0.x, g0.y, g0.z, g0.w, g1.x, g1.y, g1.z, g1.w};
    const float bb[8] = {b0.x, b0.y, b0.z, b0.w, b1.x, b1.y, b1.z, b1.w};
#pragma unroll
    for (int j = 0; j < 8; ++j) v[j] = (v[j] - mean) * inv * gg[j] + bb[j];
  };

  // ================= init =================
  if (tid < 256) div_ls[tid] = expf((float)(2 * tid) * PE_NEG);
  {
    const int gtid = widx * NTH + tid;
    if (gtid < 2 * 8 * 512) {  // v_mem = mem @ Wv.T + bv
      const int b = gtid & 7, r = (gtid >> 3) & 511, l = gtid >> 12;
      const float4* a4 = (const float4*)(memory + (size_t)b * 512);
      const float4* w4 = (const float4*)(ca_in_w + ((size_t)l * 1536 + 1024 + r) * 512);
      float s = 0.f;
      for (int i = 0; i < 128; ++i) {
        const float4 a = a4[i], ww = w4[i];
        s = fmaf(a.x, ww.x, s); s = fmaf(a.y, ww.y, s);
        s = fmaf(a.z, ww.z, s); s = fmaf(a.w, ww.w, s);
      }
      st_dev(&cav[((size_t)l * 8 + b) * 512 + r], s + ca_in_b[l * 1536 + 1024 + r]);
    }
  }
  wsync();
  {
    const int gtid = widx * NTH + tid;
    if (gtid < 2 * 8 * 512) {  // ca_const = v_mem @ Wout.T + bout
      const int b = gtid & 7, r = (gtid >> 3) & 511, l = gtid >> 12;
      const float* a = cav + ((size_t)l * 8 + b) * 512;
      const float4* w4 = (const float4*)(ca_out_w + ((size_t)l * 512 + r) * 512);
      float s = 0.f;
      for (int i = 0; i < 128; ++i) {
        const float4 ww = w4[i];
        s = fmaf(ld_dev(a + 4 * i + 0), ww.x, s);
        s = fmaf(ld_dev(a + 4 * i + 1), ww.y, s);
        s = fmaf(ld_dev(a + 4 * i + 2), ww.z, s);
        s = fmaf(ld_dev(a + 4 * i + 3), ww.w, s);
      }
      st_dev(&cac[((size_t)l * 8 + b) * 512 + r], s + ca_out_b[l * 512 + r]);
    }
  }
  wsync();

  // ================= autoregressive decode =================
  float x0r[8];   // layer input (residual for LN1), batch ab, wave-redundant
  float x2r[8];   // LN2 output (residual into FF path), batch ab
  if (tid < 8) tok_ls[tid] = 1;  // SOS
  __syncthreads();

  for (int t = 0; t < L; ++t) {
    for (int l = 0; l < 2; ++l) {
      // ---------- input build for batch ab (all waves redundant) ----------
      if (l == 0) {
        const int tok = tok_ls[ab];
        const float4* e4 = (const float4*)(embedding + (size_t)tok * 512 + col0);
        const float4 e0 = e4[0], e1 = e4[1];
        float v[8] = {e0.x, e0.y, e0.z, e0.w, e1.x, e1.y, e1.z, e1.w};
#pragma unroll
        for (int j = 0; j < 8; ++j) {
          const int c = col0 + j;
          const float ang = (float)t * div_ls[c >> 1];
          v[j] += (c & 1) ? cosf(ang) : sinf(ang);
          x0r[j] = v[j];
        }
        if (w == 0) {
#pragma unroll
          for (int j = 0; j < 8; ++j) xs[ab * 512 + col0 + j] = v[j];
        }
        __syncthreads();
      } else {
        // x = LN3_l0(x2 + sum_h p2 + ff2_b(l0))
        float v[8];
#pragma unroll
        for (int jj = 0; jj < 4; ++jj) {
          float sx = 0.f, sy = 0.f;
#pragma unroll
          for (int h = 0; h < 8; ++h) {
            const float2 p = ld_dev2((const float2*)(p2w + ((size_t)ab * 8 + h) * 512 + col0) + jj);
            sx += p.x; sy += p.y;
          }
          v[2 * jj]     = x2r[2 * jj]     + sx + ff2_b[col0 + 2 * jj];
          v[2 * jj + 1] = x2r[2 * jj + 1] + sy + ff2_b[col0 + 2 * jj + 1];
        }
        wave_ln(v, ln3_g, ln3_b);  // layer-0 LN3 params
#pragma unroll
        for (int j = 0; j < 8; ++j) x0r[j] = v[j];
        if (w == 0) {
#pragma unroll
          for (int j = 0; j < 8; ++j) xs[ab * 512 + col0 + j] = v[j];
        }
        __syncthreads();
      }

      // ---------- QKV slices (own batch, own head) ----------
      {
        for (int it = 0; it < 6; ++it) {
          const int rr = grp + 32 * it;            // 0..191
          const int type = rr >> 6, d = rr & 63;
          const int wrow = type * 512 + ah * 64 + d;
          const float4* wr = (const float4*)(sa_in_w + ((size_t)l * 1536 + wrow) * 512);
          const float4* a4 = (const float4*)(xs + (size_t)ab * 512);
          float s = 0.f;
#pragma unroll
          for (int i = 0; i < 8; ++i) {
            const float4 ww = wr[gl + 16 * i], a = a4[gl + 16 * i];
            s = fmaf(ww.x, a.x, s); s = fmaf(ww.y, a.y, s);
            s = fmaf(ww.z, a.z, s); s = fmaf(ww.w, a.w, s);
          }
          s += __shfl_xor(s, 1);
          s += __shfl_xor(s, 2);
          s += __shfl_xor(s, 4);
          s += __shfl_xor(s, 8);
          if (gl == 0) {
            s += sa_in_b[l * 1536 + wrow];
            if (type == 0)      q_s[d] = s;
            else if (type == 1) kch[l][t][d] = s;
            else                vch[l][t][d] = s;
          }
        }
        __syncthreads();
        // scores: wave w handles keys w, w+8, ...
        for (int j = w; j <= t; j += 8) {
          float s = q_s[lane] * kch[l][j][lane];
          s += __shfl_xor(s, 1);
          s += __shfl_xor(s, 2);
          s += __shfl_xor(s, 4);
          s += __shfl_xor(s, 8);
          s += __shfl_xor(s, 16);
          s += __shfl_xor(s, 32);
          if (lane == 0) p_l[j] = s * 0.125f;
        }
        __syncthreads();
        float mx = -3.4e38f;
        for (int j = 0; j <= t; ++j) mx = fmaxf(mx, p_l[j]);
        __syncthreads();
        if (tid <= t) p_l[tid] = expf(p_l[tid] - mx);
        __syncthreads();
        if (w == 0) {   // PV + normalize -> LDS (no workspace round-trip)
          float den = 0.f, o = 0.f;
          for (int j = 0; j <= t; ++j) {
            const float p = p_l[j];
            den += p;
            o = fmaf(p, vch[l][j][lane], o);
          }
          o_s[lane] = o / den;
        }
        __syncthreads();
      }

      // ---------- out-proj column-slice partial (no barrier before) ----------
      // p1[ab][ah][r] = dot(o_s[64], Wout[r][ah*64..+64)), r = 0..511.
      {
        const float4 oo = ((const float4*)o_s)[gl];
        for (int it = 0; it < 16; ++it) {
          const int r = it * 32 + grp;
          const float4 ww = ((const float4*)(sa_out_w + ((size_t)l * 512 + r) * 512 + ah * 64))[gl];
          float s = ww.x * oo.x;
          s = fmaf(ww.y, oo.y, s);
          s = fmaf(ww.z, oo.z, s);
          s = fmaf(ww.w, oo.w, s);
          s += __shfl_xor(s, 1);
          s += __shfl_xor(s, 2);
          s += __shfl_xor(s, 4);
          s += __shfl_xor(s, 8);
          if (gl == 0) st_dev(&p1w[((size_t)ab * 8 + ah) * 512 + r], s);
        }
      }
      wsync();  // barrier X1: out-proj partials visible

      // ---------- LN1(sum partials) + ca + LN2 ----------
      {
        float v[8];
#pragma unroll
        for (int jj = 0; jj < 4; ++jj) {
          float sx = 0.f, sy = 0.f;
#pragma unroll
          for (int h = 0; h < 8; ++h) {
            const float2 p = ld_dev2((const float2*)(p1w + ((size_t)ab * 8 + h) * 512 + col0) + jj);
            sx += p.x; sy += p.y;
          }
          v[2 * jj]     = x0r[2 * jj]     + sx + sa_out_b[l * 512 + col0 + 2 * jj];
          v[2 * jj + 1] = x0r[2 * jj + 1] + sy + sa_out_b[l * 512 + col0 + 2 * jj + 1];
        }
        wave_ln(v, ln1_g + l * 512, ln1_b + l * 512);
#pragma unroll
        for (int j = 0; j < 8; ++j) v[j] += ld_dev(cac + ((size_t)l * 8 + ab) * 512 + col0 + j);
        wave_ln(v, ln2_g + l * 512, ln2_b + l * 512);
#pragma unroll
        for (int j = 0; j < 8; ++j) x2r[j] = v[j];
        if (l == 1 && ah == 0 && w == 0) {   // publish x2 for final x3 rebuild
#pragma unroll
          for (int j = 0; j < 8; ++j) st_dev(&x2pb[(size_t)ab * 512 + col0 + j], v[j]);
        }
        if (w == 0) {
#pragma unroll
          for (int j = 0; j < 8; ++j) xs[ab * 512 + col0 + j] = v[j];
        }
        __syncthreads();
      }

      // ---------- FF1 rows [ah*256,+256) of own batch -> LDS ----------
      {
        const float4* a4 = (const float4*)(xs + (size_t)ab * 512);
        for (int it = 0; it < 8; ++it) {
          const int rl = it * 32 + grp;            // 0..255
          const int r  = ah * 256 + rl;
          const float4* wr = (const float4*)(ff1_w + ((size_t)l * HF + r) * 512);
          float s = 0.f;
#pragma unroll
          for (int i = 0; i < 8; ++i) {
            const float4 ww = wr[gl + 16 * i], a = a4[gl + 16 * i];
            s = fmaf(ww.x, a.x, s); s = fmaf(ww.y, a.y, s);
            s = fmaf(ww.z, a.z, s); s = fmaf(ww.w, a.w, s);
          }
          s += __shfl_xor(s, 1);
          s += __shfl_xor(s, 2);
          s += __shfl_xor(s, 4);
          s += __shfl_xor(s, 8);
          if (gl == 0) hffs[rl] = fmaxf(s + ff1_b[l * HF + r], 0.f);
        }
        __syncthreads();
      }

      // ---------- FF2 column-slice partial ----------
      // p2[ab][ah][r] = dot(hffs[256], Wff2[r][ah*256..+256)), r = 0..511.
      {
        for (int it = 0; it < 16; ++it) {
          const int r = it * 32 + grp;
          const float4* wr = (const float4*)(ff2_w + ((size_t)l * 512 + r) * HF + ah * 256);
          float s = 0.f;
#pragma unroll
          for (int i = 0; i < 4; ++i) {
            const float4 ww = wr[gl + 16 * i];
            const float4 hh = ((const float4*)hffs)[gl + 16 * i];
            s = fmaf(ww.x, hh.x, s); s = fmaf(ww.y, hh.y, s);
            s = fmaf(ww.z, hh.z, s); s = fmaf(ww.w, hh.w, s);
          }
          s += __shfl_xor(s, 1);
          s += __shfl_xor(s, 2);
          s += __shfl_xor(s, 4);
          s += __shfl_xor(s, 8);
          if (gl == 0) st_dev(&p2w[((size_t)ab * 8 + ah) * 512 + r], s);
        }
      }
      wsync();  // barrier X2: FF2 partials (+x2 publish on l==1) visible
    }  // layer loop

    // ---------- final x3 for ALL batches (wave w = batch w) ----------
    {
      float v[8];
#pragma unroll
      for (int jj = 0; jj < 4; ++jj) {
        const float2 xp = ld_dev2((const float2*)(x2pb + (size_t)w * 512 + col0) + jj);
        float sx = 0.f, sy = 0.f;
#pragma unroll
        for (int h = 0; h < 8; ++h) {
          const float2 p = ld_dev2((const float2*)(p2w + ((size_t)w * 8 + h) * 512 + col0) + jj);
          sx += p.x; sy += p.y;
        }
        v[2 * jj]     = xp.x + sx + ff2_b[512 + col0 + 2 * jj];
        v[2 * jj + 1] = xp.y + sy + ff2_b[512 + col0 + 2 * jj + 1];
      }
      wave_ln(v, ln3_g + 512, ln3_b + 512);
#pragma unroll
      for (int j = 0; j < 8; ++j) xs[w * 512 + col0 + j] = v[j];
      __syncthreads();
    }

    // ---------- logits: contiguous slab [widx*500,+500) (round-3 proven) ----------
    {
      const int rbase = widx * VPB;
      float bestv = -3.4e38f, besti = 0.f;   // valid on lanes gl<8
      for (int it = 0; it < 16; ++it) {
        const int rloc = it * 32 + grp;      // 0..511; active < 500
        if (rloc < VPB) {
          const f4v* wr = (const f4v*)(out_w + (size_t)(rbase + rloc) * 512);
          float acc[8] = {0.f, 0.f, 0.f, 0.f, 0.f, 0.f, 0.f, 0.f};
#pragma unroll
          for (int i = 0; i < 8; ++i) {
            const f4v ww = wr[gl + 16 * i];
#pragma unroll
            for (int b = 0; b < 8; ++b) {
              const float4 a = ((const float4*)(xs + b * 512))[gl + 16 * i];
              acc[b] = fmaf(ww[0], a.x, acc[b]);
              acc[b] = fmaf(ww[1], a.y, acc[b]);
              acc[b] = fmaf(ww[2], a.z, acc[b]);
              acc[b] = fmaf(ww[3], a.w, acc[b]);
            }
          }
#pragma unroll
          for (int b = 0; b < 8; ++b) {
            float v = acc[b];
            v += __shfl_xor(v, 1);
            v += __shfl_xor(v, 2);
            v += __shfl_xor(v, 4);
            v += __shfl_xor(v, 8);
            acc[b] = v;
          }
          if (gl < 8) {
            const float val = acc[gl] + out_b[rbase + rloc];
            ltile[gl][rloc] = val;
            if (val > bestv) { bestv = val; besti = (float)(rbase + rloc); }
          }
        }
      }
      if (gl < 8) gcand[grp * 8 + gl] = make_float2(bestv, besti);
      __syncthreads();   // ltile + gcand complete
#pragma unroll
      for (int b = 0; b < 8; ++b) {
        if (tid < VPB)
          __builtin_nontemporal_store(ltile[b][tid],
                                      &dlog[((size_t)b * L + t) * V + rbase + tid]);
      }
      if (tid < 8) {
        float bv = -3.4e38f, bi = 0.f;
        for (int g2 = 0; g2 < NGRP; ++g2) {
          const float2 cv = gcand[g2 * 8 + tid];
          if (cv.x > bv || (cv.x == bv && cv.y < bi)) { bv = cv.x; bi = cv.y; }
        }
        st_dev2(&cand[(size_t)widx * 8 + tid], make_float2(bv, bi));
      }
    }
    wsync();  // barrier E: all 64 candidate rows visible

    // ---------- every block reduces 64x8 candidates locally ----------
    {
      if (tid < 64) {
        const int b = tid & 7, j0 = (tid >> 3) << 3;
        float bv = -3.4e38f, bi = 0.f;
#pragma unroll
        for (int jj = 0; jj < 8; ++jj) {
          const float2 cv = ld_dev2(&cand[(size_t)(j0 + jj) * 8 + b]);
          if (cv.x > bv || (cv.x == bv && cv.y < bi)) { bv = cv.x; bi = cv.y; }
        }
        redc[tid] = make_float2(bv, bi);
      }
      __syncthreads();
      if (tid < 8) {
        float bv = -3.4e38f, bi = 0.f;
        for (int c = 0; c < 8; ++c) {
          const float2 cv = redc[c * 8 + tid];
          if (cv.x > bv || (cv.x == bv && cv.y < bi)) { bv = cv.x; bi = cv.y; }
        }
        tok_ls[tid] = (int)bi;
        if (widx == 0) dout[(size_t)tid * L + t] = bi;
      }
      __syncthreads();
    }
  }  // t loop
}

extern "C" void kernel_launch(void* const* d_in, const int* in_sizes, int n_in,
                              void* d_out, int out_size, void* d_ws, size_t ws_size,
                              hipStream_t stream) {
  (void)in_sizes; (void)n_in; (void)out_size; (void)ws_size;
  hipMemsetAsync(d_ws, 0, 8192, stream);  // barrier flags

  const float* memory    = (const float*)d_in[0];
  const float* embedding = (const float*)d_in[1];
  const float* sa_in_w   = (const float*)d_in[2];
  const float* sa_in_b   = (const float*)d_in[3];
  const float* sa_out_w  = (const float*)d_in[4];
  const float* sa_out_b  = (const float*)d_in[5];
  const float* ca_in_w   = (const float*)d_in[6];
  const float* ca_in_b   = (const float*)d_in[7];
  const float* ca_out_w  = (const float*)d_in[8];
  const float* ca_out_b  = (const float*)d_in[9];
  const float* ff1_w     = (const float*)d_in[10];
  const float* ff1_b     = (const float*)d_in[11];
  const float* ff2_w     = (const float*)d_in[12];
  const float* ff2_b     = (const float*)d_in[13];
  const float* ln1_g     = (const float*)d_in[14];
  const float* ln1_b     = (const float*)d_in[15];
  const float* ln2_g     = (const float*)d_in[16];
  const float* ln2_b     = (const float*)d_in[17];
  const float* ln3_g     = (const float*)d_in[18];
  const float* ln3_b     = (const float*)d_in[19];
  const float* out_w     = (const float*)d_in[20];
  const float* out_b     = (const float*)d_in[21];
  const int*   max_len   = (const int*)d_in[22];

  hipLaunchKernelGGL(decoder_persistent, dim3(NBK), dim3(NTH), 0, stream,
                     memory, embedding, sa_in_w, sa_in_b, sa_out_w, sa_out_b,
                     ca_in_w, ca_in_b, ca_out_w, ca_out_b, ff1_w, ff1_b,
                     ff2_w, ff2_b, ln1_g, ln1_b, ln2_g, ln2_b, ln3_g, ln3_b,
                     out_w, out_b, max_len, (float*)d_out, (float*)d_ws);
}

// Round 7
// 8775.793 us; speedup vs baseline: 1.2973x; 1.2973x over previous
//
#include <hip/hip_runtime.h>
#include <math.h>

// Persistent greedy transformer decoder, MI355X (gfx950).
// B=8, D=512, NH=8 (hd=64), H=2048, NL=2, V=32000, L=48.
// Round-8: round-3 structure verbatim (64 blocks, 9 flag-barriers/step,
// contiguous row-partitioned GEMVs, LDS KV cache, 500-row logits slab) +
// two latency cuts, nothing else:
//  1) arrive/await barrier split: each barrier window prefetches the NEXT
//     phase's weight row into registers (8 x float4), so the weight-load
//     latency overlaps the barrier wait instead of serializing after it.
//     sched_barrier(0) pins the loads before the poll loop.
//  2) out_w logits reads are __builtin_nontemporal_load: the 1 MB/block
//     slab has zero intra-step reuse and was flushing the per-XCD L2
//     (8 blocks x 1 MB vs 4 MB L2) every step, forcing all stack weights
//     back to L3. nt keeps layer weights L2-resident across steps.

#define NBK 64
#define NTH 512
#define NGRP 32

namespace cfg {
constexpr int D  = 512;
constexpr int HF = 2048;
constexpr int V  = 32000;
constexpr int TMAX = 64;        // LDS KV slots (>= L)
constexpr int VPB  = V / NBK;   // 500 logits rows per block
constexpr float EPS = 1e-5f;
constexpr float PE_NEG = -0.017988946039015984f;  // -ln(10000)/512

// workspace float offsets; u32 [0..2047] = barrier flags (64 x 128B)
constexpr size_t O_CAV  = 4096;
constexpr size_t O_CAC  = O_CAV + 2 * 8 * 512;
constexpr size_t O_ATT  = O_CAC + 2 * 8 * 512;
constexpr size_t O_Y1   = O_ATT + 8 * 512;
constexpr size_t O_Y2   = O_Y1  + 8 * 512;
constexpr size_t O_HFF  = O_Y2  + 8 * 512;
constexpr size_t O_CAND = O_HFF + 8 * 2048;
}

typedef float f4v __attribute__((ext_vector_type(4)));

// device-coherent (cross-XCD) accesses for inter-block communication
__device__ __forceinline__ float ld_dev(const float* p) {
  return __hip_atomic_load(p, __ATOMIC_RELAXED, __HIP_MEMORY_SCOPE_AGENT);
}
__device__ __forceinline__ void st_dev(float* p, float v) {
  __hip_atomic_store(p, v, __ATOMIC_RELAXED, __HIP_MEMORY_SCOPE_AGENT);
}
union F2U { float2 f; unsigned long long u; };
__device__ __forceinline__ float2 ld_dev2(const float2* p) {
  F2U x; x.u = __hip_atomic_load((const unsigned long long*)p, __ATOMIC_RELAXED, __HIP_MEMORY_SCOPE_AGENT);
  return x.f;
}
__device__ __forceinline__ void st_dev2(float2* p, float2 v) {
  F2U x; x.f = v;
  __hip_atomic_store((unsigned long long*)p, x.u, __ATOMIC_RELAXED, __HIP_MEMORY_SCOPE_AGENT);
}
__device__ __forceinline__ unsigned ld_devu(const unsigned* p) {
  return __hip_atomic_load(p, __ATOMIC_RELAXED, __HIP_MEMORY_SCOPE_AGENT);
}
__device__ __forceinline__ void st_devu(unsigned* p, unsigned v) {
  __hip_atomic_store(p, v, __ATOMIC_RELAXED, __HIP_MEMORY_SCOPE_AGENT);
}

__launch_bounds__(NTH)
__global__ void decoder_persistent(
    const float* __restrict__ memory, const float* __restrict__ embedding,
    const float* __restrict__ sa_in_w, const float* __restrict__ sa_in_b,
    const float* __restrict__ sa_out_w, const float* __restrict__ sa_out_b,
    const float* __restrict__ ca_in_w, const float* __restrict__ ca_in_b,
    const float* __restrict__ ca_out_w, const float* __restrict__ ca_out_b,
    const float* __restrict__ ff1_w, const float* __restrict__ ff1_b,
    const float* __restrict__ ff2_w, const float* __restrict__ ff2_b,
    const float* __restrict__ ln1_g, const float* __restrict__ ln1_b,
    const float* __restrict__ ln2_g, const float* __restrict__ ln2_b,
    const float* __restrict__ ln3_g, const float* __restrict__ ln3_b,
    const float* __restrict__ out_w, const float* __restrict__ out_b,
    const int* __restrict__ max_len_p,
    float* __restrict__ dout, float* __restrict__ wsf) {
  using namespace cfg;
  __shared__ __align__(16) float xs[8192];            // 32 KB activations
  __shared__ float kch[2][TMAX][64];                  // 32 KB LDS K cache
  __shared__ float vch[2][TMAX][64];                  // 32 KB LDS V cache
  __shared__ float ltile[8][VPB + 16];                // 16.5 KB logits tile
  __shared__ float q_s[64];
  __shared__ float p_l[64];
  __shared__ float div_ls[256];                       // PE frequency table
  __shared__ float2 redc[64];
  __shared__ float2 gcand[NGRP * 8];
  __shared__ int tok_ls[8];

  const int tid  = threadIdx.x;
  const int w    = tid >> 6;    // wave id == batch row for LN mapping
  const int lane = tid & 63;
  const int col0 = lane * 8;
  const int gl   = tid & 15;
  const int grp  = tid >> 4;
  const int L    = max_len_p[0];
  const int widx = (int)blockIdx.x;
  const int ab = widx >> 3;     // worker batch
  const int ah = widx & 7;      // worker head

  unsigned* wflag = (unsigned*)wsf;   // 64 flags, stride 32 u32 (128 B)

  float*  cav  = wsf + O_CAV;
  float*  cac  = wsf + O_CAC;
  float*  attb = wsf + O_ATT;
  float*  y1   = wsf + O_Y1;
  float*  y2   = wsf + O_Y2;
  float*  hff  = wsf + O_HFF;
  float2* cand = (float2*)(wsf + O_CAND);
  float*  dlog = dout + (size_t)8 * L;

  unsigned wbarn = 0;
  float4 pf[8];   // barrier-window weight prefetch (reused serially)

  // arrive/await split of the RMW-free flag barrier (round-3 mechanism).
  auto arrive = [&]() {
    __syncthreads();            // phase stores drained (vmcnt) before flag
    ++wbarn;
    if (tid == 0) st_devu(&wflag[widx * 32], wbarn);
  };
  auto await = [&]() {
    if (w == 0) {
      while (true) {
        const unsigned v = ld_devu(&wflag[lane * 32]);
        if (__ballot(v < wbarn) == 0ull) break;
        __builtin_amdgcn_s_sleep(1);
      }
    }
    __syncthreads();
  };
  auto wsync = [&]() { arrive(); await(); };

  // ---- barrier-window weight prefetchers (8 x float4 into pf) ----
  auto pref_qkv = [&](int l) {           // QKV it=0 row: type0, d=grp
    const float4* wr = (const float4*)(sa_in_w + ((size_t)l * 1536 + ah * 64 + grp) * 512);
#pragma unroll
    for (int i = 0; i < 8; ++i) pf[i] = wr[gl + 16 * i];
    __builtin_amdgcn_sched_barrier(0);
  };
  auto pref_op = [&](int l) {            // out-proj row (grp<8 active)
    const int r = (grp & 7) * 64 + widx;
    const float4* wr = (const float4*)(sa_out_w + ((size_t)l * 512 + r) * 512);
#pragma unroll
    for (int i = 0; i < 8; ++i) pf[i] = wr[gl + 16 * i];
    __builtin_amdgcn_sched_barrier(0);
  };
  auto pref_ff1 = [&](int l) {           // FF1 row (all 32 groups)
    const int r = grp * 64 + widx;
    const float4* wr = (const float4*)(ff1_w + ((size_t)l * HF + r) * 512);
#pragma unroll
    for (int i = 0; i < 8; ++i) pf[i] = wr[gl + 16 * i];
    __builtin_amdgcn_sched_barrier(0);
  };
  auto pref_ff2 = [&](int l) {           // FF2 tile0 first half (grp<8 active)
    const int r = (grp & 7) * 64 + widx;
    const float4* wr = (const float4*)(ff2_w + ((size_t)l * 512 + r) * HF);
#pragma unroll
    for (int i = 0; i < 8; ++i) pf[i] = wr[gl + 16 * i];
    __builtin_amdgcn_sched_barrier(0);
  };
  auto pref_log = [&]() {                // logits it=0 row (nt)
    const f4v* wr = (const f4v*)(out_w + (size_t)(widx * VPB + grp) * 512);
#pragma unroll
    for (int i = 0; i < 8; ++i) {
      const f4v v = __builtin_nontemporal_load(wr + gl + 16 * i);
      pf[i] = make_float4(v[0], v[1], v[2], v[3]);
    }
    __builtin_amdgcn_sched_barrier(0);
  };

  // wave-local LayerNorm of row w held in v[8] (cols col0..col0+7)
  auto wave_ln = [&](float (&v)[8], const float* g, const float* bta) {
    float s = 0.f, s2 = 0.f;
#pragma unroll
    for (int j = 0; j < 8; ++j) { s += v[j]; s2 = fmaf(v[j], v[j], s2); }
#pragma unroll
    for (int m = 1; m < 64; m <<= 1) { s += __shfl_xor(s, m); s2 += __shfl_xor(s2, m); }
    const float mean = s * (1.f / 512.f);
    const float var  = s2 * (1.f / 512.f) - mean * mean;
    const float inv  = 1.0f / sqrtf(var + EPS);
    const float4 g0 = ((const float4*)(g + col0))[0], g1 = ((const float4*)(g + col0))[1];
    const float4 b0 = ((const float4*)(bta + col0))[0], b1 = ((const float4*)(bta + col0))[1];
    const float gg[8] = {g0.x, g0.y, g0.z, g0.w, g1.x, g1.y, g1.z, g1.w};
    const float bb[8] = {b0.x, b0.y, b0.z, b0.w, b1.x, b1.y, b1.z, b1.w};
#pragma unroll
    for (int j = 0; j < 8; ++j) v[j] = (v[j] - mean) * inv * gg[j] + bb[j];
  };

  // ================= init =================
  if (tid < 256) div_ls[tid] = expf((float)(2 * tid) * PE_NEG);
  {
    const int gtid = widx * NTH + tid;
    if (gtid < 2 * 8 * 512) {  // v_mem = mem @ Wv.T + bv
      const int b = gtid & 7, r = (gtid >> 3) & 511, l = gtid >> 12;
      const float4* a4 = (const float4*)(memory + (size_t)b * 512);
      const float4* w4 = (const float4*)(ca_in_w + ((size_t)l * 1536 + 1024 + r) * 512);
      float s = 0.f;
      for (int i = 0; i < 128; ++i) {
        const float4 a = a4[i], ww = w4[i];
        s = fmaf(a.x, ww.x, s); s = fmaf(a.y, ww.y, s);
        s = fmaf(a.z, ww.z, s); s = fmaf(a.w, ww.w, s);
      }
      st_dev(&cav[((size_t)l * 8 + b) * 512 + r], s + ca_in_b[l * 1536 + 1024 + r]);
    }
  }
  wsync();
  {
    const int gtid = widx * NTH + tid;
    if (gtid < 2 * 8 * 512) {  // ca_const = v_mem @ Wout.T + bout
      const int b = gtid & 7, r = (gtid >> 3) & 511, l = gtid >> 12;
      const float* a = cav + ((size_t)l * 8 + b) * 512;
      const float4* w4 = (const float4*)(ca_out_w + ((size_t)l * 512 + r) * 512);
      float s = 0.f;
      for (int i = 0; i < 128; ++i) {
        const float4 ww = w4[i];
        s = fmaf(ld_dev(a + 4 * i + 0), ww.x, s);
        s = fmaf(ld_dev(a + 4 * i + 1), ww.y, s);
        s = fmaf(ld_dev(a + 4 * i + 2), ww.z, s);
        s = fmaf(ld_dev(a + 4 * i + 3), ww.w, s);
      }
      st_dev(&cac[((size_t)l * 8 + b) * 512 + r], s + ca_out_b[l * 512 + r]);
    }
  }
  wsync();

  // ================= autoregressive decode =================
  float x0r[8];   // residual for LN1
  float x2r[8];   // LN2 output (residual for LN3)
  if (tid < 8) tok_ls[tid] = 1;  // SOS
  __syncthreads();

  pref_qkv(0);    // initial prefetch (no prior window)

  for (int t = 0; t < L; ++t) {
    for (int l = 0; l < 2; ++l) {
      // ---------- build layer input rows into xs (+ x0r regs) ----------
      if (l == 0) {
        const int tok = tok_ls[w];
        const float4* e4 = (const float4*)(embedding + (size_t)tok * 512 + col0);
        const float4 e0 = e4[0], e1 = e4[1];
        float v[8] = {e0.x, e0.y, e0.z, e0.w, e1.x, e1.y, e1.z, e1.w};
#pragma unroll
        for (int j = 0; j < 8; ++j) {
          const int c = col0 + j;
          const float ang = (float)t * div_ls[c >> 1];
          v[j] += (c & 1) ? cosf(ang) : sinf(ang);
          x0r[j] = v[j];
          xs[w * 512 + c] = v[j];
        }
        __syncthreads();
      } else {
        float v[8];
#pragma unroll
        for (int j = 0; j < 8; ++j) v[j] = x2r[j] + ld_dev(y2 + (size_t)w * 512 + col0 + j);
        wave_ln(v, ln3_g, ln3_b);  // layer-0 LN3
#pragma unroll
        for (int j = 0; j < 8; ++j) { x0r[j] = v[j]; xs[w * 512 + col0 + j] = v[j]; }
        __syncthreads();
      }

      // ---------- fused QKV-slice + attention (block-local) ----------
      {
        const float4* a4 = (const float4*)(xs + (size_t)ab * 512);
        // it = 0 from prefetched pf (type0, d=grp)
        {
          float s = 0.f;
#pragma unroll
          for (int i = 0; i < 8; ++i) {
            const float4 ww = pf[i], a = a4[gl + 16 * i];
            s = fmaf(ww.x, a.x, s); s = fmaf(ww.y, a.y, s);
            s = fmaf(ww.z, a.z, s); s = fmaf(ww.w, a.w, s);
          }
          s += __shfl_xor(s, 1);
          s += __shfl_xor(s, 2);
          s += __shfl_xor(s, 4);
          s += __shfl_xor(s, 8);
          if (gl == 0) q_s[grp] = s + sa_in_b[l * 1536 + ah * 64 + grp];
        }
        for (int it = 1; it < 6; ++it) {
          const int rr = grp + 32 * it;            // 32..191
          const int type = rr >> 6, d = rr & 63;
          const int wrow = type * 512 + ah * 64 + d;
          const float4* wr = (const float4*)(sa_in_w + ((size_t)l * 1536 + wrow) * 512);
          float s = 0.f;
#pragma unroll
          for (int i = 0; i < 8; ++i) {
            const float4 ww = wr[gl + 16 * i], a = a4[gl + 16 * i];
            s = fmaf(ww.x, a.x, s); s = fmaf(ww.y, a.y, s);
            s = fmaf(ww.z, a.z, s); s = fmaf(ww.w, a.w, s);
          }
          s += __shfl_xor(s, 1);
          s += __shfl_xor(s, 2);
          s += __shfl_xor(s, 4);
          s += __shfl_xor(s, 8);
          if (gl == 0) {
            s += sa_in_b[l * 1536 + wrow];
            if (type == 0)      q_s[d] = s;
            else if (type == 1) kch[l][t][d] = s;
            else                vch[l][t][d] = s;
          }
        }
        __syncthreads();
        // scores: wave w handles keys w, w+8, ...
        for (int j = w; j <= t; j += 8) {
          float s = q_s[lane] * kch[l][j][lane];
          s += __shfl_xor(s, 1);
          s += __shfl_xor(s, 2);
          s += __shfl_xor(s, 4);
          s += __shfl_xor(s, 8);
          s += __shfl_xor(s, 16);
          s += __shfl_xor(s, 32);
          if (lane == 0) p_l[j] = s * 0.125f;
        }
        __syncthreads();
        float mx = -3.4e38f;
        for (int j = 0; j <= t; ++j) mx = fmaxf(mx, p_l[j]);
        __syncthreads();
        if (tid <= t) p_l[tid] = expf(p_l[tid] - mx);
        __syncthreads();
        if (w == 0) {   // PV + normalize, 64 lanes = 64 dims
          float den = 0.f, o = 0.f;
          for (int j = 0; j <= t; ++j) {
            const float p = p_l[j];
            den += p;
            o = fmaf(p, vch[l][j][lane], o);
          }
          st_dev(&attb[(size_t)ab * 512 + ah * 64 + lane], o / den);
        }
      }
      arrive();  // barrier A
      pref_op(l);
      await();

      // ---------- attention out-proj (row r, grp<8; weights in pf) ----------
      for (int j = tid; j < 2048; j += NTH)
        ((float2*)xs)[j] = ld_dev2((const float2*)attb + j);
      __syncthreads();
      if (grp < 8) {
        const int r = grp * 64 + widx;
        float acc[8] = {0.f, 0.f, 0.f, 0.f, 0.f, 0.f, 0.f, 0.f};
#pragma unroll
        for (int i = 0; i < 8; ++i) {
          const float4 ww = pf[i];
#pragma unroll
          for (int b = 0; b < 8; ++b) {
            const float4 a = ((const float4*)(xs + b * 512))[gl + 16 * i];
            acc[b] = fmaf(ww.x, a.x, acc[b]);
            acc[b] = fmaf(ww.y, a.y, acc[b]);
            acc[b] = fmaf(ww.z, a.z, acc[b]);
            acc[b] = fmaf(ww.w, a.w, acc[b]);
          }
        }
#pragma unroll
        for (int b = 0; b < 8; ++b) {
          float v = acc[b];
          v += __shfl_xor(v, 1);
          v += __shfl_xor(v, 2);
          v += __shfl_xor(v, 4);
          v += __shfl_xor(v, 8);
          acc[b] = v;
        }
        if (gl < 8) st_dev(&y1[(size_t)gl * 512 + r], acc[gl] + sa_out_b[l * 512 + r]);
      }
      arrive();  // barrier B
      pref_ff1(l);
      await();

      // ---------- LN1 + ca_const + LN2 (in regs) then FF1 (pf weights) ----------
      {
        float v[8];
#pragma unroll
        for (int j = 0; j < 8; ++j) v[j] = x0r[j] + ld_dev(y1 + (size_t)w * 512 + col0 + j);
        wave_ln(v, ln1_g + l * 512, ln1_b + l * 512);
#pragma unroll
        for (int j = 0; j < 8; ++j) v[j] += ld_dev(cac + ((size_t)l * 8 + w) * 512 + col0 + j);
        wave_ln(v, ln2_g + l * 512, ln2_b + l * 512);
#pragma unroll
        for (int j = 0; j < 8; ++j) { x2r[j] = v[j]; xs[w * 512 + col0 + j] = v[j]; }
        __syncthreads();
      }
      {
        const int r = grp * 64 + widx;     // < 2048, all groups active
        float acc[8] = {0.f, 0.f, 0.f, 0.f, 0.f, 0.f, 0.f, 0.f};
#pragma unroll
        for (int i = 0; i < 8; ++i) {
          const float4 ww = pf[i];
#pragma unroll
          for (int b = 0; b < 8; ++b) {
            const float4 a = ((const float4*)(xs + b * 512))[gl + 16 * i];
            acc[b] = fmaf(ww.x, a.x, acc[b]);
            acc[b] = fmaf(ww.y, a.y, acc[b]);
            acc[b] = fmaf(ww.z, a.z, acc[b]);
            acc[b] = fmaf(ww.w, a.w, acc[b]);
          }
        }
#pragma unroll
        for (int b = 0; b < 8; ++b) {
          float v = acc[b];
          v += __shfl_xor(v, 1);
          v += __shfl_xor(v, 2);
          v += __shfl_xor(v, 4);
          v += __shfl_xor(v, 8);
          acc[b] = v;
        }
        if (gl < 8)
          st_dev(&hff[(size_t)gl * HF + r], fmaxf(acc[gl] + ff1_b[l * HF + r], 0.f));
      }
      arrive();  // barrier C
      pref_ff2(l);
      await();

      // ---------- FF2 (K=2048, two 1024 tiles; tile0 first half from pf) ----------
      {
        const bool act = (grp < 8);
        const int r = (grp & 7) * 64 + widx;
        float acc[8] = {0.f, 0.f, 0.f, 0.f, 0.f, 0.f, 0.f, 0.f};
        for (int tile = 0; tile < 2; ++tile) {
          __syncthreads();
          for (int j = tid; j < 4096; j += NTH)
            ((float2*)xs)[j] = ld_dev2((const float2*)hff + (size_t)(j >> 9) * 1024 +
                                       tile * 512 + (j & 511));
          __syncthreads();
          if (act) {
            const float4* wr = (const float4*)(ff2_w + ((size_t)l * 512 + r) * HF +
                                               (size_t)tile * 1024);
#pragma unroll
            for (int i = 0; i < 16; ++i) {
              const float4 ww = (tile == 0 && i < 8) ? pf[i] : wr[gl + 16 * i];
#pragma unroll
              for (int b2 = 0; b2 < 8; ++b2) {
                const float4 a = ((const float4*)xs)[b2 * 256 + gl + 16 * i];
                acc[b2] = fmaf(ww.x, a.x, acc[b2]);
                acc[b2] = fmaf(ww.y, a.y, acc[b2]);
                acc[b2] = fmaf(ww.z, a.z, acc[b2]);
                acc[b2] = fmaf(ww.w, a.w, acc[b2]);
              }
            }
          }
        }
        if (act) {
#pragma unroll
          for (int b2 = 0; b2 < 8; ++b2) {
            float v = acc[b2];
            v += __shfl_xor(v, 1);
            v += __shfl_xor(v, 2);
            v += __shfl_xor(v, 4);
            v += __shfl_xor(v, 8);
            acc[b2] = v;
          }
          if (gl < 8) st_dev(&y2[(size_t)gl * 512 + r], acc[gl] + ff2_b[l * 512 + r]);
        }
      }
      arrive();  // barrier D
      if (l == 0) pref_qkv(1); else pref_log();
      await();
    }  // layer loop

    // ---------- final LN3 -> x3 in xs ----------
    {
      float v[8];
#pragma unroll
      for (int j = 0; j < 8; ++j) v[j] = x2r[j] + ld_dev(y2 + (size_t)w * 512 + col0 + j);
      wave_ln(v, ln3_g + 512, ln3_b + 512);
#pragma unroll
      for (int j = 0; j < 8; ++j) xs[w * 512 + col0 + j] = v[j];
      __syncthreads();
    }

    // ---------- logits: contiguous slab, nt weight loads ----------
    {
      const int rbase = widx * VPB;
      float bestv = -3.4e38f, besti = 0.f;   // valid on lanes gl<8
      // it = 0 from pf
      {
        const int rloc = grp;
        float acc[8] = {0.f, 0.f, 0.f, 0.f, 0.f, 0.f, 0.f, 0.f};
#pragma unroll
        for (int i = 0; i < 8; ++i) {
          const float4 ww = pf[i];
#pragma unroll
          for (int b = 0; b < 8; ++b) {
            const float4 a = ((const float4*)(xs + b * 512))[gl + 16 * i];
            acc[b] = fmaf(ww.x, a.x, acc[b]);
            acc[b] = fmaf(ww.y, a.y, acc[b]);
            acc[b] = fmaf(ww.z, a.z, acc[b]);
            acc[b] = fmaf(ww.w, a.w, acc[b]);
          }
        }
#pragma unroll
        for (int b = 0; b < 8; ++b) {
          float v = acc[b];
          v += __shfl_xor(v, 1);
          v += __shfl_xor(v, 2);
          v += __shfl_xor(v, 4);
          v += __shfl_xor(v, 8);
          acc[b] = v;
        }
        if (gl < 8) {
          const float val = acc[gl] + out_b[rbase + rloc];
          ltile[gl][rloc] = val;
          if (val > bestv) { bestv = val; besti = (float)(rbase + rloc); }
        }
      }
      for (int it = 1; it < 16; ++it) {
        const int rloc = it * 32 + grp;      // 32..511; active < 500
        if (rloc < VPB) {
          const f4v* wr = (const f4v*)(out_w + (size_t)(rbase + rloc) * 512);
          float acc[8] = {0.f, 0.f, 0.f, 0.f, 0.f, 0.f, 0.f, 0.f};
#pragma unroll
          for (int i = 0; i < 8; ++i) {
            const f4v ww = __builtin_nontemporal_load(wr + gl + 16 * i);
#pragma unroll
            for (int b = 0; b < 8; ++b) {
              const float4 a = ((const float4*)(xs + b * 512))[gl + 16 * i];
              acc[b] = fmaf(ww[0], a.x, acc[b]);
              acc[b] = fmaf(ww[1], a.y, acc[b]);
              acc[b] = fmaf(ww[2], a.z, acc[b]);
              acc[b] = fmaf(ww[3], a.w, acc[b]);
            }
          }
#pragma unroll
          for (int b = 0; b < 8; ++b) {
            float v = acc[b];
            v += __shfl_xor(v, 1);
            v += __shfl_xor(v, 2);
            v += __shfl_xor(v, 4);
            v += __shfl_xor(v, 8);
            acc[b] = v;
          }
          if (gl < 8) {
            const float val = acc[gl] + out_b[rbase + rloc];
            ltile[gl][rloc] = val;
            if (val > bestv) { bestv = val; besti = (float)(rbase + rloc); }
          }
        }
      }
      if (gl < 8) gcand[grp * 8 + gl] = make_float2(bestv, besti);
      __syncthreads();   // ltile + gcand complete
      // coalesced bulk store: 500 contiguous floats per batch
#pragma unroll
      for (int b = 0; b < 8; ++b) {
        if (tid < VPB)
          __builtin_nontemporal_store(ltile[b][tid],
                                      &dlog[((size_t)b * L + t) * V + rbase + tid]);
      }
      if (tid < 8) {
        float bv = -3.4e38f, bi = 0.f;
        for (int g2 = 0; g2 < NGRP; ++g2) {
          const float2 cv = gcand[g2 * 8 + tid];
          if (cv.x > bv || (cv.x == bv && cv.y < bi)) { bv = cv.x; bi = cv.y; }
        }
        st_dev2(&cand[(size_t)widx * 8 + tid], make_float2(bv, bi));
      }
    }
    arrive();  // barrier E
    pref_qkv(0);   // next step's QKV (harmless on last step)
    await();

    // ---------- every block reduces 64x8 candidates locally ----------
    {
      if (tid < 64) {
        const int b = tid & 7, j0 = (tid >> 3) << 3;
        float bv = -3.4e38f, bi = 0.f;
#pragma unroll
        for (int jj = 0; jj < 8; ++jj) {
          const float2 cv = ld_dev2(&cand[(size_t)(j0 + jj) * 8 + b]);
          if (cv.x > bv || (cv.x == bv && cv.y < bi)) { bv = cv.x; bi = cv.y; }
        }
        redc[tid] = make_float2(bv, bi);
      }
      __syncthreads();
      if (tid < 8) {
        float bv = -3.4e38f, bi = 0.f;
        for (int c = 0; c < 8; ++c) {
          const float2 cv = redc[c * 8 + tid];
          if (cv.x > bv || (cv.x == bv && cv.y < bi)) { bv = cv.x; bi = cv.y; }
        }
        tok_ls[tid] = (int)bi;
        if (widx == 0) dout[(size_t)tid * L + t] = bi;
      }
      __syncthreads();
    }
  }  // t loop
}

extern "C" void kernel_launch(void* const* d_in, const int* in_sizes, int n_in,
                              void* d_out, int out_size, void* d_ws, size_t ws_size,
                              hipStream_t stream) {
  (void)in_sizes; (void)n_in; (void)out_size; (void)ws_size;
  hipMemsetAsync(d_ws, 0, 16384, stream);  // barrier flags

  const float* memory    = (const float*)d_in[0];
  const float* embedding = (const float*)d_in[1];
  const float* sa_in_w   = (const float*)d_in[2];
  const float* sa_in_b   = (const float*)d_in[3];
  const float* sa_out_w  = (const float*)d_in[4];
  const float* sa_out_b  = (const float*)d_in[5];
  const float* ca_in_w   = (const float*)d_in[6];
  const float* ca_in_b   = (const float*)d_in[7];
  const float* ca_out_w  = (const float*)d_in[8];
  const float* ca_out_b  = (const float*)d_in[9];
  const float* ff1_w     = (const float*)d_in[10];
  const float* ff1_b     = (const float*)d_in[11];
  const float* ff2_w     = (const float*)d_in[12];
  const float* ff2_b     = (const float*)d_in[13];
  const float* ln1_g     = (const float*)d_in[14];
  const float* ln1_b     = (const float*)d_in[15];
  const float* ln2_g     = (const float*)d_in[16];
  const float* ln2_b     = (const float*)d_in[17];
  const float* ln3_g     = (const float*)d_in[18];
  const float* ln3_b     = (const float*)d_in[19];
  const float* out_w     = (const float*)d_in[20];
  const float* out_b     = (const float*)d_in[21];
  const int*   max_len   = (const int*)d_in[22];

  hipLaunchKernelGGL(decoder_persistent, dim3(NBK), dim3(NTH), 0, stream,
                     memory, embedding, sa_in_w, sa_in_b, sa_out_w, sa_out_b,
                     ca_in_w, ca_in_b, ca_out_w, ca_out_b, ff1_w, ff1_b,
                     ff2_w, ff2_b, ln1_g, ln1_b, ln2_g, ln2_b, ln3_g, ln3_b,
                     out_w, out_b, max_len, (float*)d_out, (float*)d_ws);
}

// Round 8
// 7769.223 us; speedup vs baseline: 1.4654x; 1.1296x over previous
//
#include <hip/hip_runtime.h>
#include <math.h>

// Persistent greedy transformer decoder, MI355X (gfx950).
// B=8, D=512, NH=8 (hd=64), H=2048, NL=2, V=32000, L=48.
// Round-9: round-3 champion (5541us) ported to NTH=1024 (16 waves/CU, 4/SIMD)
// -- ONE mechanism: double TLP to hide latency; all memory access patterns,
// barriers, and partitioning identical to round-3. QKV serial depth 6->3,
// logits serial depth 16->8, staging loops halve. NO nt weight reads
// (round-7 proved they regress); nt only on dlog output stores.
// Per-batch LN phases guarded to waves 0..7 (waves 8..15 idle there).

#define NBK 64
#define NTH 1024
#define NGRP 64

namespace cfg {
constexpr int D  = 512;
constexpr int HF = 2048;
constexpr int V  = 32000;
constexpr int TMAX = 64;        // LDS KV slots (>= L)
constexpr int VPB  = V / NBK;   // 500 logits rows per block
constexpr float EPS = 1e-5f;
constexpr float PE_NEG = -0.017988946039015984f;  // -ln(10000)/512

// workspace float offsets; u32 [0..2047] = barrier flags (64 x 128B)
constexpr size_t O_CAV  = 4096;
constexpr size_t O_CAC  = O_CAV + 2 * 8 * 512;
constexpr size_t O_ATT  = O_CAC + 2 * 8 * 512;
constexpr size_t O_Y1   = O_ATT + 8 * 512;
constexpr size_t O_Y2   = O_Y1  + 8 * 512;
constexpr size_t O_HFF  = O_Y2  + 8 * 512;
constexpr size_t O_CAND = O_HFF + 8 * 2048;
}

typedef float f4v __attribute__((ext_vector_type(4)));

// device-coherent (cross-XCD) accesses for inter-block communication
__device__ __forceinline__ float ld_dev(const float* p) {
  return __hip_atomic_load(p, __ATOMIC_RELAXED, __HIP_MEMORY_SCOPE_AGENT);
}
__device__ __forceinline__ void st_dev(float* p, float v) {
  __hip_atomic_store(p, v, __ATOMIC_RELAXED, __HIP_MEMORY_SCOPE_AGENT);
}
union F2U { float2 f; unsigned long long u; };
__device__ __forceinline__ float2 ld_dev2(const float2* p) {
  F2U x; x.u = __hip_atomic_load((const unsigned long long*)p, __ATOMIC_RELAXED, __HIP_MEMORY_SCOPE_AGENT);
  return x.f;
}
__device__ __forceinline__ void st_dev2(float2* p, float2 v) {
  F2U x; x.f = v;
  __hip_atomic_store((unsigned long long*)p, x.u, __ATOMIC_RELAXED, __HIP_MEMORY_SCOPE_AGENT);
}
__device__ __forceinline__ unsigned ld_devu(const unsigned* p) {
  return __hip_atomic_load(p, __ATOMIC_RELAXED, __HIP_MEMORY_SCOPE_AGENT);
}
__device__ __forceinline__ void st_devu(unsigned* p, unsigned v) {
  __hip_atomic_store(p, v, __ATOMIC_RELAXED, __HIP_MEMORY_SCOPE_AGENT);
}

// GEMV stage: out[b][r] = dot(xs_row[b], W[r]) + bias[r], K = 512, 8 batches.
// Rows strided r = grp*NW + bid (NW = #participating blocks).
template <typename EPI>
__device__ __forceinline__ void gemv512(const float* __restrict__ W,
                                        const float* __restrict__ bias,
                                        int R, int NW, int bid,
                                        const float* xs, EPI&& epi) {
  const int tid = threadIdx.x;
  const int gl  = tid & 15;
  const int grp = tid >> 4;
  for (int r = grp * NW + bid; r < R; r += NW * NGRP) {
    const f4v* wr = (const f4v*)(W + (size_t)r * cfg::D);
    float acc[8] = {0.f, 0.f, 0.f, 0.f, 0.f, 0.f, 0.f, 0.f};
#pragma unroll
    for (int i = 0; i < 8; ++i) {
      const f4v w = wr[gl + 16 * i];
#pragma unroll
      for (int b = 0; b < 8; ++b) {
        const float4 a = ((const float4*)(xs + b * cfg::D))[gl + 16 * i];
        acc[b] = fmaf(w[0], a.x, acc[b]);
        acc[b] = fmaf(w[1], a.y, acc[b]);
        acc[b] = fmaf(w[2], a.z, acc[b]);
        acc[b] = fmaf(w[3], a.w, acc[b]);
      }
    }
#pragma unroll
    for (int b = 0; b < 8; ++b) {
      float v = acc[b];
      v += __shfl_xor(v, 1);
      v += __shfl_xor(v, 2);
      v += __shfl_xor(v, 4);
      v += __shfl_xor(v, 8);
      acc[b] = v;
    }
    if (gl < 8) {
      float v = acc[gl];
      if (bias) v += bias[r];
      epi(gl, r, v);
    }
  }
}

__launch_bounds__(NTH)
__global__ void decoder_persistent(
    const float* __restrict__ memory, const float* __restrict__ embedding,
    const float* __restrict__ sa_in_w, const float* __restrict__ sa_in_b,
    const float* __restrict__ sa_out_w, const float* __restrict__ sa_out_b,
    const float* __restrict__ ca_in_w, const float* __restrict__ ca_in_b,
    const float* __restrict__ ca_out_w, const float* __restrict__ ca_out_b,
    const float* __restrict__ ff1_w, const float* __restrict__ ff1_b,
    const float* __restrict__ ff2_w, const float* __restrict__ ff2_b,
    const float* __restrict__ ln1_g, const float* __restrict__ ln1_b,
    const float* __restrict__ ln2_g, const float* __restrict__ ln2_b,
    const float* __restrict__ ln3_g, const float* __restrict__ ln3_b,
    const float* __restrict__ out_w, const float* __restrict__ out_b,
    const int* __restrict__ max_len_p,
    float* __restrict__ dout, float* __restrict__ wsf) {
  using namespace cfg;
  __shared__ __align__(16) float xs[8192];            // 32 KB activations
  __shared__ float kch[2][TMAX][64];                  // 32 KB LDS K cache
  __shared__ float vch[2][TMAX][64];                  // 32 KB LDS V cache
  __shared__ float ltile[8][VPB + 16];                // 16.5 KB logits tile
  __shared__ float q_s[64];
  __shared__ float p_l[64];
  __shared__ float div_ls[256];                       // PE frequency table
  __shared__ float2 redc[64];
  __shared__ float2 gcand[NGRP * 8];
  __shared__ int tok_ls[8];

  const int tid  = threadIdx.x;
  const int w    = tid >> 6;    // wave id 0..15
  const int bw   = w & 7;       // batch row for LN mapping (waves 8..15 idle)
  const int lane = tid & 63;
  const int col0 = lane * 8;
  const int gl   = tid & 15;
  const int grp  = tid >> 4;    // 0..63
  const int L    = max_len_p[0];
  const int widx = (int)blockIdx.x;
  const int ab = widx >> 3;     // worker batch
  const int ah = widx & 7;      // worker head

  unsigned* wflag = (unsigned*)wsf;   // 64 flags, stride 32 u32 (128 B)

  float*  cav  = wsf + O_CAV;
  float*  cac  = wsf + O_CAC;
  float*  attb = wsf + O_ATT;
  float*  y1   = wsf + O_Y1;
  float*  y2   = wsf + O_Y2;
  float*  hff  = wsf + O_HFF;
  float2* cand = (float2*)(wsf + O_CAND);
  float*  dlog = dout + (size_t)8 * L;

  unsigned wbarn = 0;

  // RMW-free 64-block flag barrier (round-3 mechanism, proven).
  auto wsync = [&]() {
    __syncthreads();
    ++wbarn;
    if (tid == 0) st_devu(&wflag[widx * 32], wbarn);
    if (w == 0) {
      while (true) {
        const unsigned v = ld_devu(&wflag[lane * 32]);
        if (__ballot(v < wbarn) == 0ull) break;
        __builtin_amdgcn_s_sleep(1);
      }
    }
    __syncthreads();
  };

  // wave-local LayerNorm of row bw held in v[8] (cols col0..col0+7)
  auto wave_ln = [&](float (&v)[8], const float* g, const float* bta) {
    float s = 0.f, s2 = 0.f;
#pragma unroll
    for (int j = 0; j < 8; ++j) { s += v[j]; s2 = fmaf(v[j], v[j], s2); }
#pragma unroll
    for (int m = 1; m < 64; m <<= 1) { s += __shfl_xor(s, m); s2 += __shfl_xor(s2, m); }
    const float mean = s * (1.f / 512.f);
    const float var  = s2 * (1.f / 512.f) - mean * mean;
    const float inv  = 1.0f / sqrtf(var + EPS);
    const float4 g0 = ((const float4*)(g + col0))[0], g1 = ((const float4*)(g + col0))[1];
    const float4 b0 = ((const float4*)(bta + col0))[0], b1 = ((const float4*)(bta + col0))[1];
    const float gg[8] = {g0.x, g0.y, g0.z, g0.w, g1.x, g1.y, g1.z, g1.w};
    const float bb[8] = {b0.x, b0.y, b0.z, b0.w, b1.x, b1.y, b1.z, b1.w};
#pragma unroll
    for (int j = 0; j < 8; ++j) v[j] = (v[j] - mean) * inv * gg[j] + bb[j];
  };

  // ================= init =================
  if (tid < 256) div_ls[tid] = expf((float)(2 * tid) * PE_NEG);
  {
    const int gtid = widx * NTH + tid;
    if (gtid < 2 * 8 * 512) {  // v_mem = mem @ Wv.T + bv (blocks 0..7)
      const int b = gtid & 7, r = (gtid >> 3) & 511, l = gtid >> 12;
      const float4* a4 = (const float4*)(memory + (size_t)b * 512);
      const float4* w4 = (const float4*)(ca_in_w + ((size_t)l * 1536 + 1024 + r) * 512);
      float s = 0.f;
      for (int i = 0; i < 128; ++i) {
        const float4 a = a4[i], ww = w4[i];
        s = fmaf(a.x, ww.x, s); s = fmaf(a.y, ww.y, s);
        s = fmaf(a.z, ww.z, s); s = fmaf(a.w, ww.w, s);
      }
      st_dev(&cav[((size_t)l * 8 + b) * 512 + r], s + ca_in_b[l * 1536 + 1024 + r]);
    }
  }
  wsync();
  {
    const int gtid = widx * NTH + tid;
    if (gtid < 2 * 8 * 512) {  // ca_const = v_mem @ Wout.T + bout
      const int b = gtid & 7, r = (gtid >> 3) & 511, l = gtid >> 12;
      const float* a = cav + ((size_t)l * 8 + b) * 512;
      const float4* w4 = (const float4*)(ca_out_w + ((size_t)l * 512 + r) * 512);
      float s = 0.f;
      for (int i = 0; i < 128; ++i) {
        const float4 ww = w4[i];
        s = fmaf(ld_dev(a + 4 * i + 0), ww.x, s);
        s = fmaf(ld_dev(a + 4 * i + 1), ww.y, s);
        s = fmaf(ld_dev(a + 4 * i + 2), ww.z, s);
        s = fmaf(ld_dev(a + 4 * i + 3), ww.w, s);
      }
      st_dev(&cac[((size_t)l * 8 + b) * 512 + r], s + ca_out_b[l * 512 + r]);
    }
  }
  wsync();

  // ================= autoregressive decode =================
  float x0r[8];   // residual for LN1 (valid on waves 0..7)
  float x2r[8];   // LN2 output (residual for LN3)
  if (tid < 8) tok_ls[tid] = 1;  // SOS
  __syncthreads();

  for (int t = 0; t < L; ++t) {
    for (int l = 0; l < 2; ++l) {
      // ---------- build layer input rows into xs (+ x0r regs), waves 0..7 ----
      if (l == 0) {
        if (w < 8) {
          const int tok = tok_ls[bw];
          const float4* e4 = (const float4*)(embedding + (size_t)tok * 512 + col0);
          const float4 e0 = e4[0], e1 = e4[1];
          float v[8] = {e0.x, e0.y, e0.z, e0.w, e1.x, e1.y, e1.z, e1.w};
#pragma unroll
          for (int j = 0; j < 8; ++j) {
            const int c = col0 + j;
            const float ang = (float)t * div_ls[c >> 1];
            v[j] += (c & 1) ? cosf(ang) : sinf(ang);
            x0r[j] = v[j];
            xs[bw * 512 + c] = v[j];
          }
        }
        __syncthreads();
      } else {
        if (w < 8) {
          float v[8];
#pragma unroll
          for (int j = 0; j < 8; ++j) v[j] = x2r[j] + ld_dev(y2 + (size_t)bw * 512 + col0 + j);
          wave_ln(v, ln3_g, ln3_b);  // layer-0 LN3
#pragma unroll
          for (int j = 0; j < 8; ++j) { x0r[j] = v[j]; xs[bw * 512 + col0 + j] = v[j]; }
        }
        __syncthreads();
      }

      // ---------- fused QKV-slice + attention (block-local, no barrier) ----
      {
        // 192 rows over 64 groups: 3 serial iterations (was 6).
        for (int it = 0; it < 3; ++it) {
          const int rr = grp + 64 * it;            // 0..191
          const int type = rr >> 6, d = rr & 63;
          const int wrow = type * 512 + ah * 64 + d;
          const float4* wr = (const float4*)(sa_in_w + ((size_t)l * 1536 + wrow) * 512);
          const float4* a4 = (const float4*)(xs + (size_t)ab * 512);
          float s = 0.f;
#pragma unroll
          for (int i = 0; i < 8; ++i) {
            const float4 ww = wr[gl + 16 * i], a = a4[gl + 16 * i];
            s = fmaf(ww.x, a.x, s); s = fmaf(ww.y, a.y, s);
            s = fmaf(ww.z, a.z, s); s = fmaf(ww.w, a.w, s);
          }
          s += __shfl_xor(s, 1);
          s += __shfl_xor(s, 2);
          s += __shfl_xor(s, 4);
          s += __shfl_xor(s, 8);
          if (gl == 0) {
            s += sa_in_b[l * 1536 + wrow];
            if (type == 0)      q_s[d] = s;
            else if (type == 1) kch[l][t][d] = s;
            else                vch[l][t][d] = s;
          }
        }
        __syncthreads();
        // scores: wave w handles keys w, w+16, ...
        for (int j = w; j <= t; j += 16) {
          float s = q_s[lane] * kch[l][j][lane];
          s += __shfl_xor(s, 1);
          s += __shfl_xor(s, 2);
          s += __shfl_xor(s, 4);
          s += __shfl_xor(s, 8);
          s += __shfl_xor(s, 16);
          s += __shfl_xor(s, 32);
          if (lane == 0) p_l[j] = s * 0.125f;
        }
        __syncthreads();
        float mx = -3.4e38f;
        for (int j = 0; j <= t; ++j) mx = fmaxf(mx, p_l[j]);
        __syncthreads();
        if (tid <= t) p_l[tid] = expf(p_l[tid] - mx);
        __syncthreads();
        if (w == 0) {   // PV + normalize, 64 lanes = 64 dims
          float den = 0.f, o = 0.f;
          for (int j = 0; j <= t; ++j) {
            const float p = p_l[j];
            den += p;
            o = fmaf(p, vch[l][j][lane], o);
          }
          st_dev(&attb[(size_t)ab * 512 + ah * 64 + lane], o / den);
        }
      }
      wsync();  // barrier A: attn slices visible

      // ---------- attention out-proj ----------
      for (int j = tid; j < 2048; j += NTH)
        ((float2*)xs)[j] = ld_dev2((const float2*)attb + j);
      __syncthreads();
      gemv512(sa_out_w + (size_t)l * 512 * 512, sa_out_b + l * 512, 512,
              NBK, widx, xs,
              [&](int b, int r, float val) { st_dev(&y1[(size_t)b * 512 + r], val); });
      wsync();  // barrier B: y1 complete

      // ---------- LN1 + ca_const + LN2 (in regs, waves 0..7) then FF1 ----------
      if (w < 8) {
        float v[8];
#pragma unroll
        for (int j = 0; j < 8; ++j) v[j] = x0r[j] + ld_dev(y1 + (size_t)bw * 512 + col0 + j);
        wave_ln(v, ln1_g + l * 512, ln1_b + l * 512);
#pragma unroll
        for (int j = 0; j < 8; ++j) v[j] += ld_dev(cac + ((size_t)l * 8 + bw) * 512 + col0 + j);
        wave_ln(v, ln2_g + l * 512, ln2_b + l * 512);
#pragma unroll
        for (int j = 0; j < 8; ++j) { x2r[j] = v[j]; xs[bw * 512 + col0 + j] = v[j]; }
      }
      __syncthreads();
      gemv512(ff1_w + (size_t)l * HF * 512, ff1_b + l * HF, HF,
              NBK, widx, xs,
              [&](int b, int r, float val) {
                st_dev(&hff[(size_t)b * HF + r], fmaxf(val, 0.f));
              });
      wsync();  // barrier C: hff complete

      // ---------- FF2 (K=2048, two 1024-wide tiles) ----------
      {
        const bool act = (grp < 8);                 // 512 rows, 1 row/group
        const int r = (grp & 7) * 64 + widx;
        float acc[8] = {0.f, 0.f, 0.f, 0.f, 0.f, 0.f, 0.f, 0.f};
        for (int tile = 0; tile < 2; ++tile) {
          __syncthreads();
          for (int j = tid; j < 4096; j += NTH)
            ((float2*)xs)[j] = ld_dev2((const float2*)hff + (size_t)(j >> 9) * 1024 +
                                       tile * 512 + (j & 511));
          __syncthreads();
          if (act) {
            const float4* wr = (const float4*)(ff2_w + ((size_t)l * 512 + r) * HF +
                                               (size_t)tile * 1024);
#pragma unroll
            for (int i = 0; i < 16; ++i) {
              const float4 ww = wr[gl + 16 * i];
#pragma unroll
              for (int b2 = 0; b2 < 8; ++b2) {
                const float4 a = ((const float4*)xs)[b2 * 256 + gl + 16 * i];
                acc[b2] = fmaf(ww.x, a.x, acc[b2]);
                acc[b2] = fmaf(ww.y, a.y, acc[b2]);
                acc[b2] = fmaf(ww.z, a.z, acc[b2]);
                acc[b2] = fmaf(ww.w, a.w, acc[b2]);
              }
            }
          }
        }
        if (act) {
#pragma unroll
          for (int b2 = 0; b2 < 8; ++b2) {
            float v = acc[b2];
            v += __shfl_xor(v, 1);
            v += __shfl_xor(v, 2);
            v += __shfl_xor(v, 4);
            v += __shfl_xor(v, 8);
            acc[b2] = v;
          }
          if (gl < 8) st_dev(&y2[(size_t)gl * 512 + r], acc[gl] + ff2_b[l * 512 + r]);
        }
      }
      wsync();  // barrier D: y2 complete
    }  // layer loop

    // ---------- final LN3 -> x3 in xs (waves 0..7) ----------
    if (w < 8) {
      float v[8];
#pragma unroll
      for (int j = 0; j < 8; ++j) v[j] = x2r[j] + ld_dev(y2 + (size_t)bw * 512 + col0 + j);
      wave_ln(v, ln3_g + 512, ln3_b + 512);
#pragma unroll
      for (int j = 0; j < 8; ++j) xs[bw * 512 + col0 + j] = v[j];
    }
    __syncthreads();

    // ---------- logits: contiguous slab [widx*500,+500), cached loads ----------
    {
      const int rbase = widx * VPB;
      float bestv = -3.4e38f, besti = 0.f;   // valid on lanes gl<8
      for (int it = 0; it < 8; ++it) {
        const int rloc = it * 64 + grp;      // 0..511; active < 500
        if (rloc < VPB) {
          const f4v* wr = (const f4v*)(out_w + (size_t)(rbase + rloc) * 512);
          float acc[8] = {0.f, 0.f, 0.f, 0.f, 0.f, 0.f, 0.f, 0.f};
#pragma unroll
          for (int i = 0; i < 8; ++i) {
            const f4v ww = wr[gl + 16 * i];
#pragma unroll
            for (int b = 0; b < 8; ++b) {
              const float4 a = ((const float4*)(xs + b * 512))[gl + 16 * i];
              acc[b] = fmaf(ww[0], a.x, acc[b]);
              acc[b] = fmaf(ww[1], a.y, acc[b]);
              acc[b] = fmaf(ww[2], a.z, acc[b]);
              acc[b] = fmaf(ww[3], a.w, acc[b]);
            }
          }
#pragma unroll
          for (int b = 0; b < 8; ++b) {
            float v = acc[b];
            v += __shfl_xor(v, 1);
            v += __shfl_xor(v, 2);
            v += __shfl_xor(v, 4);
            v += __shfl_xor(v, 8);
            acc[b] = v;
          }
          if (gl < 8) {
            const float val = acc[gl] + out_b[rbase + rloc];
            ltile[gl][rloc] = val;
            if (val > bestv) { bestv = val; besti = (float)(rbase + rloc); }
          }
        }
      }
      if (gl < 8) gcand[grp * 8 + gl] = make_float2(bestv, besti);
      __syncthreads();   // ltile + gcand complete
      // coalesced bulk store: 500 contiguous floats per batch
#pragma unroll
      for (int b = 0; b < 8; ++b) {
        if (tid < VPB)
          __builtin_nontemporal_store(ltile[b][tid],
                                      &dlog[((size_t)b * L + t) * V + rbase + tid]);
      }
      if (tid < 8) {
        float bv = -3.4e38f, bi = 0.f;
        for (int g2 = 0; g2 < NGRP; ++g2) {
          const float2 cv = gcand[g2 * 8 + tid];
          if (cv.x > bv || (cv.x == bv && cv.y < bi)) { bv = cv.x; bi = cv.y; }
        }
        st_dev2(&cand[(size_t)widx * 8 + tid], make_float2(bv, bi));
      }
    }
    wsync();  // barrier E: all 64 candidate rows visible

    // ---------- every block reduces 64x8 candidates locally ----------
    {
      if (tid < 64) {
        const int b = tid & 7, j0 = (tid >> 3) << 3;
        float bv = -3.4e38f, bi = 0.f;
#pragma unroll
        for (int jj = 0; jj < 8; ++jj) {
          const float2 cv = ld_dev2(&cand[(size_t)(j0 + jj) * 8 + b]);
          if (cv.x > bv || (cv.x == bv && cv.y < bi)) { bv = cv.x; bi = cv.y; }
        }
        redc[tid] = make_float2(bv, bi);
      }
      __syncthreads();
      if (tid < 8) {
        float bv = -3.4e38f, bi = 0.f;
        for (int c = 0; c < 8; ++c) {
          const float2 cv = redc[c * 8 + tid];
          if (cv.x > bv || (cv.x == bv && cv.y < bi)) { bv = cv.x; bi = cv.y; }
        }
        tok_ls[tid] = (int)bi;
        if (widx == 0) dout[(size_t)tid * L + t] = bi;
      }
      __syncthreads();
    }
  }  // t loop
}

extern "C" void kernel_launch(void* const* d_in, const int* in_sizes, int n_in,
                              void* d_out, int out_size, void* d_ws, size_t ws_size,
                              hipStream_t stream) {
  (void)in_sizes; (void)n_in; (void)out_size; (void)ws_size;
  hipMemsetAsync(d_ws, 0, 16384, stream);  // barrier flags

  const float* memory    = (const float*)d_in[0];
  const float* embedding = (const float*)d_in[1];
  const float* sa_in_w   = (const float*)d_in[2];
  const float* sa_in_b   = (const float*)d_in[3];
  const float* sa_out_w  = (const float*)d_in[4];
  const float* sa_out_b  = (const float*)d_in[5];
  const float* ca_in_w   = (const float*)d_in[6];
  const float* ca_in_b   = (const float*)d_in[7];
  const float* ca_out_w  = (const float*)d_in[8];
  const float* ca_out_b  = (const float*)d_in[9];
  const float* ff1_w     = (const float*)d_in[10];
  const float* ff1_b     = (const float*)d_in[11];
  const float* ff2_w     = (const float*)d_in[12];
  const float* ff2_b     = (const float*)d_in[13];
  const float* ln1_g     = (const float*)d_in[14];
  const float* ln1_b     = (const float*)d_in[15];
  const float* ln2_g     = (const float*)d_in[16];
  const float* ln2_b     = (const float*)d_in[17];
  const float* ln3_g     = (const float*)d_in[18];
  const float* ln3_b     = (const float*)d_in[19];
  const float* out_w     = (const float*)d_in[20];
  const float* out_b     = (const float*)d_in[21];
  const int*   max_len   = (const int*)d_in[22];

  hipLaunchKernelGGL(decoder_persistent, dim3(NBK), dim3(NTH), 0, stream,
                     memory, embedding, sa_in_w, sa_in_b, sa_out_w, sa_out_b,
                     ca_in_w, ca_in_b, ca_out_w, ca_out_b, ff1_w, ff1_b,
                     ff2_w, ff2_b, ln1_g, ln1_b, ln2_g, ln2_b, ln3_g, ln3_b,
                     out_w, out_b, max_len, (float*)d_out, (float*)d_ws);
}